// Round 4
// baseline (499.020 us; speedup 1.0000x reference)
//
#include <hip/hip_runtime.h>
#include <math.h>

#define BS 64
#define NN 1024
#define T  1200
#define NSEQ (BS * NN)   // 65536

#define NBLK   1024      // 4 blocks/CU, persistent
#define WAVES  (NBLK * 4)        // 4096 waves
#define ITERS  (NSEQ / WAVES)    // 16 sequences per wave

// Wave-private sync: all data flow is intra-wave (one sequence per wave).
#define WAVE_SYNC() asm volatile("s_waitcnt lgkmcnt(0)" ::: "memory")

__global__ __launch_bounds__(256) void chain_kernel(
    const float* __restrict__ x,
    const float* __restrict__ c0_w, const float* __restrict__ c0_b,
    const float* __restrict__ c2_w, const float* __restrict__ c2_b,
    const float* __restrict__ c4_w, const float* __restrict__ c4_b,
    const float* __restrict__ c6_w, const float* __restrict__ c6_b,
    const float* __restrict__ c8_w, const float* __restrict__ c8_b,
    float* __restrict__ feat)
{
    __shared__ __align__(16) float smem[4][1400];
    const int wave = threadIdx.x >> 6;
    const int lane = threadIdx.x & 63;
    const int wid  = blockIdx.x * 4 + wave;

    float* sx = smem[wave];
    float* sB = sx + 1200;
    float4* sx4 = (float4*)sx;

    const float w00 = c0_w[0], w01 = c0_w[1], b0 = c0_b[0];
    const float w20 = c2_w[0], w21 = c2_w[1], w22 = c2_w[2], w23 = c2_w[3], b2 = c2_b[0];
    const float w40 = c4_w[0], w41 = c4_w[1], w42 = c4_w[2], w43 = c4_w[3], b4 = c4_b[0];
    const float w60 = c6_w[0], w61 = c6_w[1], w62 = c6_w[2], w63 = c6_w[3], b6 = c6_b[0];
    const float w80 = c8_w[0], w81 = c8_w[1], w82 = c8_w[2], b8 = c8_b[0];

    const bool tail = lane < 44;                    // 300 float4 = 4*64 + 44

    const float4* xg4 = (const float4*)(x + (size_t)wid * T);
    float4 r0 = xg4[lane];
    float4 r1 = xg4[lane + 64];
    float4 r2 = xg4[lane + 128];
    float4 r3 = xg4[lane + 192];
    float4 r4 = make_float4(0.f, 0.f, 0.f, 0.f);
    if (tail) r4 = xg4[lane + 256];

    for (int it = 0; it < ITERS; ++it) {
        const int seq = it * WAVES + wid;

        sx4[lane]       = r0;
        sx4[lane + 64]  = r1;
        sx4[lane + 128] = r2;
        sx4[lane + 192] = r3;
        if (tail) sx4[lane + 256] = r4;
        WAVE_SYNC();

        if (it + 1 < ITERS) {
            const float4* xn4 = (const float4*)(x + (size_t)(seq + WAVES) * T);
            r0 = xn4[lane];
            r1 = xn4[lane + 64];
            r2 = xn4[lane + 128];
            r3 = xn4[lane + 192];
            if (tail) r4 = xn4[lane + 256];
        }

        // stage1: conv1(k2,s2)+pool3+relu : 1200 -> 200
#pragma unroll
        for (int sub = 0; sub < 4; ++sub) {
            int p = lane + sub * 64;
            if (p < 200) {
                const float* xp = sx + 6 * p;
                float x0 = xp[0], x1 = xp[1], x2 = xp[2], x3 = xp[3], x4v = xp[4], x5 = xp[5];
                float cA = fmaf(w00, x0, fmaf(w01, x1, b0));
                float cB = fmaf(w00, x2, fmaf(w01, x3, b0));
                float cC = fmaf(w00, x4v, fmaf(w01, x5, b0));
                sB[p] = fmaxf(fmaxf(fmaxf(cA, cB), cC), 0.0f);
            }
        }
        WAVE_SYNC();

        // stage2: conv2(k4,s2,p1)+pool2+relu : 200 -> 50
        if (lane < 50) {
            int base = 4 * lane - 1;
            float v0 = sB[base < 0 ? 0 : base];
            float v1 = sB[base + 1];
            float v2 = sB[base + 2];
            float v3 = sB[base + 3];
            float v4 = sB[base + 4];
            float v5 = sB[(base + 5) > 199 ? 199 : (base + 5)];
            if (lane == 0)  v0 = 0.0f;
            if (lane == 49) v5 = 0.0f;
            float oa = fmaf(w20, v0, fmaf(w21, v1, fmaf(w22, v2, fmaf(w23, v3, b2))));
            float ob = fmaf(w20, v2, fmaf(w21, v3, fmaf(w22, v4, fmaf(w23, v5, b2))));
            sx[lane] = fmaxf(fmaxf(oa, ob), 0.0f);
        }
        WAVE_SYNC();

        // stage3: conv3(k4,s2,p1)+pool2+relu : 50 -> 12
        if (lane < 12) {
            int base = 4 * lane - 1;
            float u0 = sx[base < 0 ? 0 : base];
            float u1 = sx[base + 1];
            float u2 = sx[base + 2];
            float u3 = sx[base + 3];
            float u4 = sx[base + 4];
            float u5 = sx[base + 5];
            if (lane == 0) u0 = 0.0f;
            float oa = fmaf(w40, u0, fmaf(w41, u1, fmaf(w42, u2, fmaf(w43, u3, b4))));
            float ob = fmaf(w40, u2, fmaf(w41, u3, fmaf(w42, u4, fmaf(w43, u5, b4))));
            sx[64 + lane] = fmaxf(fmaxf(oa, ob), 0.0f);
        }
        WAVE_SYNC();

        // stage4: conv4(k4,s2,p1)+pool2+relu+conv5(k3) : 12 -> 1
        if (lane == 0) {
            float a3[14];
            a3[0] = 0.0f; a3[13] = 0.0f;
#pragma unroll
            for (int j = 0; j < 12; ++j) a3[j + 1] = sx[64 + j];
            float o[6];
#pragma unroll
            for (int j = 0; j < 6; ++j) {
                o[j] = fmaf(w60, a3[2 * j], fmaf(w61, a3[2 * j + 1],
                       fmaf(w62, a3[2 * j + 2], fmaf(w63, a3[2 * j + 3], b6))));
            }
            float A40 = fmaxf(fmaxf(o[0], o[1]), 0.0f);
            float A41 = fmaxf(fmaxf(o[2], o[3]), 0.0f);
            float A42 = fmaxf(fmaxf(o[4], o[5]), 0.0f);
            feat[seq] = fmaf(w80, A40, fmaf(w81, A41, fmaf(w82, A42, b8)));
        }
        WAVE_SYNC();
    }
}

__global__ __launch_bounds__(256) void head_kernel(
    const float* __restrict__ feat,
    const float* __restrict__ cls_w,
    const float* __restrict__ cls_b,
    float* __restrict__ out)
{
    const int b = blockIdx.x;
    float a0 = 0.0f, a1 = 0.0f, a2 = 0.0f;
    for (int n = threadIdx.x; n < NN; n += 256) {
        float f = feat[b * NN + n];
        a0 += f * cls_w[0 * NN + n];
        a1 += f * cls_w[1 * NN + n];
        a2 += f * cls_w[2 * NN + n];
    }
    for (int off = 32; off; off >>= 1) {
        a0 += __shfl_down(a0, off);
        a1 += __shfl_down(a1, off);
        a2 += __shfl_down(a2, off);
    }
    __shared__ float red[4][3];
    const int wave = threadIdx.x >> 6;
    const int lane = threadIdx.x & 63;
    if (lane == 0) { red[wave][0] = a0; red[wave][1] = a1; red[wave][2] = a2; }
    __syncthreads();
    if (threadIdx.x == 0) {
        float l0 = red[0][0] + red[1][0] + red[2][0] + red[3][0] + cls_b[0];
        float l1 = red[0][1] + red[1][1] + red[2][1] + red[3][1] + cls_b[1];
        float l2 = red[0][2] + red[1][2] + red[2][2] + red[3][2] + cls_b[2];
        float m  = fmaxf(l0, fmaxf(l1, l2));
        float e0 = expf(l0 - m), e1 = expf(l1 - m), e2 = expf(l2 - m);
        float inv = 1.0f / (e0 + e1 + e2);
        out[b * 3 + 0] = e0 * inv;
        out[b * 3 + 1] = e1 * inv;
        out[b * 3 + 2] = e2 * inv;
    }
}

extern "C" void kernel_launch(void* const* d_in, const int* in_sizes, int n_in,
                              void* d_out, int out_size, void* d_ws, size_t ws_size,
                              hipStream_t stream) {
    const float* x     = (const float*)d_in[0];
    const float* c0_w  = (const float*)d_in[1];
    const float* c0_b  = (const float*)d_in[2];
    const float* c2_w  = (const float*)d_in[3];
    const float* c2_b  = (const float*)d_in[4];
    const float* c4_w  = (const float*)d_in[5];
    const float* c4_b  = (const float*)d_in[6];
    const float* c6_w  = (const float*)d_in[7];
    const float* c6_b  = (const float*)d_in[8];
    const float* c8_w  = (const float*)d_in[9];
    const float* c8_b  = (const float*)d_in[10];
    const float* cls_w = (const float*)d_in[15];
    const float* cls_b = (const float*)d_in[16];

    float* feat = (float*)d_ws;   // 65536 floats = 256 KB

    // Real chain (timed contribution identical to R3).
    chain_kernel<<<NBLK, 256, 0, stream>>>(
        x, c0_w, c0_b, c2_w, c2_b, c4_w, c4_b, c6_w, c6_b, c8_w, c8_b, feat);

    // DIFFERENTIAL PROBE: identical kernel on a disjoint cold 315 MB ws region
    // (0xAA poison = normal tiny floats). dur_us(R4) - dur_us(R3) = chain dur.
    // Output goes to an unused ws region; does not touch the real feat/out path.
    const size_t probe_src_off = 64ull << 20;                       // 64 MB
    const size_t probe_out_off = 448ull << 20;                      // 448 MB
    const size_t src_need = probe_src_off + (size_t)NSEQ * T * sizeof(float);
    const size_t out_need = probe_out_off + (size_t)NSEQ * sizeof(float);
    const float* probe_src = x;
    float* probe_feat = feat;
    if (ws_size >= src_need && ws_size >= out_need) {
        probe_src  = (const float*)((const char*)d_ws + probe_src_off);
        probe_feat = (float*)((char*)d_ws + probe_out_off);
    }
    chain_kernel<<<NBLK, 256, 0, stream>>>(
        probe_src, c0_w, c0_b, c2_w, c2_b, c4_w, c4_b, c6_w, c6_b, c8_w, c8_b, probe_feat);

    head_kernel<<<BS, 256, 0, stream>>>(feat, cls_w, cls_b, (float*)d_out);
}

// Round 5
// 443.731 us; speedup vs baseline: 1.1246x; 1.1246x over previous
//
#include <hip/hip_runtime.h>
#include <math.h>

#define BS 64
#define NN 1024
#define T  1200
#define NSEQ (BS * NN)   // 65536

#define NBLK   1024      // 4 blocks/CU, persistent
#define WAVES  (NBLK * 4)        // 4096 waves
#define ITERS  (NSEQ / WAVES)    // 16 sequences per wave

// Wave-private sync: all data flow is intra-wave (one sequence per wave).
// DS ops from one wave complete in order; this waits for outstanding DS ops
// and blocks compiler reordering of LDS accesses across stage boundaries.
#define WAVE_SYNC() asm volatile("s_waitcnt lgkmcnt(0)" ::: "memory")

// Measured (R4 differential probe): this kernel runs at ~55 µs for the full
// 315 MB x read = 5.7 TB/s ≈ 91% of achievable HBM BW -> memory-roofline.

__global__ __launch_bounds__(256) void chain_kernel(
    const float* __restrict__ x,
    const float* __restrict__ c0_w, const float* __restrict__ c0_b,
    const float* __restrict__ c2_w, const float* __restrict__ c2_b,
    const float* __restrict__ c4_w, const float* __restrict__ c4_b,
    const float* __restrict__ c6_w, const float* __restrict__ c6_b,
    const float* __restrict__ c8_w, const float* __restrict__ c8_b,
    float* __restrict__ feat)
{
    __shared__ __align__(16) float smem[4][1400];
    const int wave = threadIdx.x >> 6;
    const int lane = threadIdx.x & 63;
    const int wid  = blockIdx.x * 4 + wave;

    float* sx = smem[wave];
    float* sB = sx + 1200;
    float4* sx4 = (float4*)sx;

    const float w00 = c0_w[0], w01 = c0_w[1], b0 = c0_b[0];
    const float w20 = c2_w[0], w21 = c2_w[1], w22 = c2_w[2], w23 = c2_w[3], b2 = c2_b[0];
    const float w40 = c4_w[0], w41 = c4_w[1], w42 = c4_w[2], w43 = c4_w[3], b4 = c4_b[0];
    const float w60 = c6_w[0], w61 = c6_w[1], w62 = c6_w[2], w63 = c6_w[3], b6 = c6_b[0];
    const float w80 = c8_w[0], w81 = c8_w[1], w82 = c8_w[2], b8 = c8_b[0];

    const bool tail = lane < 44;                    // 300 float4 = 4*64 + 44

    const float4* xg4 = (const float4*)(x + (size_t)wid * T);
    float4 r0 = xg4[lane];
    float4 r1 = xg4[lane + 64];
    float4 r2 = xg4[lane + 128];
    float4 r3 = xg4[lane + 192];
    float4 r4 = make_float4(0.f, 0.f, 0.f, 0.f);
    if (tail) r4 = xg4[lane + 256];

    for (int it = 0; it < ITERS; ++it) {
        const int seq = it * WAVES + wid;

        sx4[lane]       = r0;
        sx4[lane + 64]  = r1;
        sx4[lane + 128] = r2;
        sx4[lane + 192] = r3;
        if (tail) sx4[lane + 256] = r4;
        WAVE_SYNC();

        if (it + 1 < ITERS) {
            const float4* xn4 = (const float4*)(x + (size_t)(seq + WAVES) * T);
            r0 = xn4[lane];
            r1 = xn4[lane + 64];
            r2 = xn4[lane + 128];
            r3 = xn4[lane + 192];
            if (tail) r4 = xn4[lane + 256];
        }

        // stage1: conv1(k2,s2)+pool3+relu : 1200 -> 200
#pragma unroll
        for (int sub = 0; sub < 4; ++sub) {
            int p = lane + sub * 64;
            if (p < 200) {
                const float* xp = sx + 6 * p;
                float x0 = xp[0], x1 = xp[1], x2 = xp[2], x3 = xp[3], x4v = xp[4], x5 = xp[5];
                float cA = fmaf(w00, x0, fmaf(w01, x1, b0));
                float cB = fmaf(w00, x2, fmaf(w01, x3, b0));
                float cC = fmaf(w00, x4v, fmaf(w01, x5, b0));
                sB[p] = fmaxf(fmaxf(fmaxf(cA, cB), cC), 0.0f);
            }
        }
        WAVE_SYNC();

        // stage2: conv2(k4,s2,p1)+pool2+relu : 200 -> 50
        if (lane < 50) {
            int base = 4 * lane - 1;
            float v0 = sB[base < 0 ? 0 : base];
            float v1 = sB[base + 1];
            float v2 = sB[base + 2];
            float v3 = sB[base + 3];
            float v4 = sB[base + 4];
            float v5 = sB[(base + 5) > 199 ? 199 : (base + 5)];
            if (lane == 0)  v0 = 0.0f;
            if (lane == 49) v5 = 0.0f;
            float oa = fmaf(w20, v0, fmaf(w21, v1, fmaf(w22, v2, fmaf(w23, v3, b2))));
            float ob = fmaf(w20, v2, fmaf(w21, v3, fmaf(w22, v4, fmaf(w23, v5, b2))));
            sx[lane] = fmaxf(fmaxf(oa, ob), 0.0f);
        }
        WAVE_SYNC();

        // stage3: conv3(k4,s2,p1)+pool2+relu : 50 -> 12
        if (lane < 12) {
            int base = 4 * lane - 1;
            float u0 = sx[base < 0 ? 0 : base];
            float u1 = sx[base + 1];
            float u2 = sx[base + 2];
            float u3 = sx[base + 3];
            float u4 = sx[base + 4];
            float u5 = sx[base + 5];
            if (lane == 0) u0 = 0.0f;
            float oa = fmaf(w40, u0, fmaf(w41, u1, fmaf(w42, u2, fmaf(w43, u3, b4))));
            float ob = fmaf(w40, u2, fmaf(w41, u3, fmaf(w42, u4, fmaf(w43, u5, b4))));
            sx[64 + lane] = fmaxf(fmaxf(oa, ob), 0.0f);
        }
        WAVE_SYNC();

        // stage4: conv4(k4,s2,p1)+pool2+relu+conv5(k3) : 12 -> 1
        if (lane == 0) {
            float a3[14];
            a3[0] = 0.0f; a3[13] = 0.0f;
#pragma unroll
            for (int j = 0; j < 12; ++j) a3[j + 1] = sx[64 + j];
            float o[6];
#pragma unroll
            for (int j = 0; j < 6; ++j) {
                o[j] = fmaf(w60, a3[2 * j], fmaf(w61, a3[2 * j + 1],
                       fmaf(w62, a3[2 * j + 2], fmaf(w63, a3[2 * j + 3], b6))));
            }
            float A40 = fmaxf(fmaxf(o[0], o[1]), 0.0f);
            float A41 = fmaxf(fmaxf(o[2], o[3]), 0.0f);
            float A42 = fmaxf(fmaxf(o[4], o[5]), 0.0f);
            feat[seq] = fmaf(w80, A40, fmaf(w81, A41, fmaf(w82, A42, b8)));
        }
        WAVE_SYNC();
    }
}

__global__ __launch_bounds__(256) void head_kernel(
    const float* __restrict__ feat,
    const float* __restrict__ cls_w,
    const float* __restrict__ cls_b,
    float* __restrict__ out)
{
    const int b = blockIdx.x;
    float a0 = 0.0f, a1 = 0.0f, a2 = 0.0f;
    for (int n = threadIdx.x; n < NN; n += 256) {
        float f = feat[b * NN + n];
        a0 += f * cls_w[0 * NN + n];
        a1 += f * cls_w[1 * NN + n];
        a2 += f * cls_w[2 * NN + n];
    }
    for (int off = 32; off; off >>= 1) {
        a0 += __shfl_down(a0, off);
        a1 += __shfl_down(a1, off);
        a2 += __shfl_down(a2, off);
    }
    __shared__ float red[4][3];
    const int wave = threadIdx.x >> 6;
    const int lane = threadIdx.x & 63;
    if (lane == 0) { red[wave][0] = a0; red[wave][1] = a1; red[wave][2] = a2; }
    __syncthreads();
    if (threadIdx.x == 0) {
        float l0 = red[0][0] + red[1][0] + red[2][0] + red[3][0] + cls_b[0];
        float l1 = red[0][1] + red[1][1] + red[2][1] + red[3][1] + cls_b[1];
        float l2 = red[0][2] + red[1][2] + red[2][2] + red[3][2] + cls_b[2];
        float m  = fmaxf(l0, fmaxf(l1, l2));
        float e0 = expf(l0 - m), e1 = expf(l1 - m), e2 = expf(l2 - m);
        float inv = 1.0f / (e0 + e1 + e2);
        out[b * 3 + 0] = e0 * inv;
        out[b * 3 + 1] = e1 * inv;
        out[b * 3 + 2] = e2 * inv;
    }
}

extern "C" void kernel_launch(void* const* d_in, const int* in_sizes, int n_in,
                              void* d_out, int out_size, void* d_ws, size_t ws_size,
                              hipStream_t stream) {
    const float* x     = (const float*)d_in[0];
    const float* c0_w  = (const float*)d_in[1];
    const float* c0_b  = (const float*)d_in[2];
    const float* c2_w  = (const float*)d_in[3];
    const float* c2_b  = (const float*)d_in[4];
    const float* c4_w  = (const float*)d_in[5];
    const float* c4_b  = (const float*)d_in[6];
    const float* c6_w  = (const float*)d_in[7];
    const float* c6_b  = (const float*)d_in[8];
    const float* c8_w  = (const float*)d_in[9];
    const float* c8_b  = (const float*)d_in[10];
    // d_in[11..14]: gcn weights/biases — dead code in the reference, unused.
    const float* cls_w = (const float*)d_in[15];
    const float* cls_b = (const float*)d_in[16];

    float* feat = (float*)d_ws;   // 65536 floats = 256 KB

    chain_kernel<<<NBLK, 256, 0, stream>>>(
        x, c0_w, c0_b, c2_w, c2_b, c4_w, c4_b, c6_w, c6_b, c8_w, c8_b, feat);
    head_kernel<<<BS, 256, 0, stream>>>(feat, cls_w, cls_b, (float*)d_out);
}